// Round 12
// baseline (215.781 us; speedup 1.0000x reference)
//
#include <hip/hip_runtime.h>
#include <hip/hip_bf16.h>
#include <stdint.h>

typedef __bf16 bf16;
typedef __bf16 bf16x8 __attribute__((ext_vector_type(8)));
typedef float f32x4 __attribute__((ext_vector_type(4)));

#define BB   2048
#define ISZ  512
#define NN   2048
#define OSZ  128

// ---------------------------------------------------------------------------
// Fused prep: 4 pack regions (fp32 -> bf16, 8 elems/thread) + 7 transposes.
// Transpose tile = 128(k) x 32(n), wide I/O (R11-verified).
// ---------------------------------------------------------------------------
struct PackD { const float* src; bf16* dst; int W, ld, off, n8; };
struct TD    { const float* src; const float* msk; bf16* dst;
               int Ncols, ld_dst, k_off, mode, ntk, start; };  // ntk = K/128
struct PAll  { PackD p[4]; TD d[7]; int packBlocks; };

__global__ __launch_bounds__(256) void prep_all_k(PAll a) {
  if ((int)blockIdx.x < a.packBlocks) {
    int idx = blockIdx.x * 256 + threadIdx.x;
    PackD d = a.p[0]; int base = 0;
#pragma unroll
    for (int i = 1; i < 4; ++i) if (idx >= a.p[i - 1].n8) { d = a.p[i]; base = a.p[i - 1].n8; }
    if (idx >= d.n8) return;
    int e = (idx - base) * 8;
    int m = e / d.W;
    int c = e - m * d.W;
    const float4 v0 = *reinterpret_cast<const float4*>(d.src + e);
    const float4 v1 = *reinterpret_cast<const float4*>(d.src + e + 4);
    bf16x8 o;
    o[0] = (bf16)v0.x; o[1] = (bf16)v0.y; o[2] = (bf16)v0.z; o[3] = (bf16)v0.w;
    o[4] = (bf16)v1.x; o[5] = (bf16)v1.y; o[6] = (bf16)v1.z; o[7] = (bf16)v1.w;
    *reinterpret_cast<bf16x8*>(d.dst + (size_t)m * d.ld + d.off + c) = o;
    return;
  }
  int bid = blockIdx.x - a.packBlocks;
  TD d = a.d[0];
#pragma unroll
  for (int i = 1; i < 7; ++i) if (bid >= a.d[i].start) d = a.d[i];
  int local = bid - d.start;
  int k0 = (local % d.ntk) * 128;
  int n0 = (local / d.ntk) * 32;
  __shared__ float t[128][33];
  const int tx8 = threadIdx.x & 7;
  const int kr  = threadIdx.x >> 3;
  const int nc  = n0 + tx8 * 4;
#pragma unroll
  for (int i = 0; i < 4; ++i) {
    int k = k0 + kr + 32 * i;
    float4 v = *reinterpret_cast<const float4*>(d.src + (size_t)k * d.Ncols + nc);
    if (d.mode == 2) {
      float4 m = *reinterpret_cast<const float4*>(d.msk + (size_t)k * d.Ncols + nc);
      v.x *= m.x; v.y *= m.y; v.z *= m.z; v.w *= m.w;
    } else if (d.mode == 1) {
      if (k == nc)     v.x = 0.f;
      if (k == nc + 1) v.y = 0.f;
      if (k == nc + 2) v.z = 0.f;
      if (k == nc + 3) v.w = 0.f;
    }
    float* r = &t[kr + 32 * i][tx8 * 4];
    r[0] = v.x; r[1] = v.y; r[2] = v.z; r[3] = v.w;
  }
  __syncthreads();
  const int n  = threadIdx.x >> 3;
  const int kc = (threadIdx.x & 7) * 16;
  bf16x8 o0, o1;
#pragma unroll
  for (int j = 0; j < 8; ++j) {
    o0[j] = (bf16)t[kc + j][n];
    o1[j] = (bf16)t[kc + 8 + j][n];
  }
  bf16* dp = d.dst + (size_t)(n0 + n) * d.ld_dst + d.k_off + k0 + kc;
  *reinterpret_cast<bf16x8*>(dp) = o0;
  *reinterpret_cast<bf16x8*>(dp + 8) = o1;
}

// ---------------------------------------------------------------------------
// GEMM descriptor.  epi 0: blend epilogue (fp32 hin/outf + bf16 nxt)
//                   epi 1: fp32 store    epi 2: bf16 store (split partials)
// ---------------------------------------------------------------------------
struct GP {
  const bf16* A; const bf16* B;
  int K, lda, ldb;
  const float* hin; const float* bias; const float* radd;
  float* outf; int ld_out;
  bf16* nxt; int ld_nxt;
  int epi;
};

__device__ __forceinline__ void gload16(const bf16* g, bf16* l) {
  __builtin_amdgcn_global_load_lds(
      (const __attribute__((address_space(1))) void*)g,
      (__attribute__((address_space(3))) void*)l, 16, 0, 0);
}

__device__ __forceinline__ void epilogue_store(const GP& p, int row, int col, float v) {
  size_t oidx = (size_t)row * p.ld_out + col;
  if (p.epi == 0) {
    float pre = v + p.bias[col];
    if (p.radd) pre += p.radd[oidx];
    float h = p.hin[oidx] * 0.9f + fmaxf(pre, 0.f) * 0.1f;
    p.outf[oidx] = h;
    p.nxt[(size_t)row * p.ld_nxt + col] = (bf16)h;
  } else if (p.epi == 1) {
    p.outf[oidx] = v;
  } else {
    ((bf16*)p.outf)[oidx] = (bf16)v;
  }
}

// ---------------------------------------------------------------------------
// R10 winner body: 128x128 tile, 8 waves = 2x2 spatial (wave-tile 64x64) x 2
// K-slices, BK=64, dbuf 64 KB LDS, counted vmcnt, cross-slice LDS reduce,
// conflict-free swizzle.  R12: + s_setprio around the MFMA cluster (T5).
// ---------------------------------------------------------------------------
__device__ __forceinline__ void gemm_ks(const GP p) {
  __shared__ __align__(16) bf16 sm[2][2][128][64];    // 64 KB
  const int lane = threadIdx.x & 63;
  const int wave = threadIdx.x >> 6;
  const int ks = wave >> 2;
  const int sp = wave & 3;
  const int gx = gridDim.x, nwg = gx * gridDim.y;
  const int lid = blockIdx.x + gx * blockIdx.y;
  const int q = nwg >> 3;
  const int swz = (lid & 7) * q + (lid >> 3);
  const int m0 = (swz / gx) * 128, n0 = (swz % gx) * 128;
  const int wm0 = (sp >> 1) * 64, wn0 = (sp & 1) * 64;
  const int srow = lane >> 3;
  const int scol = ((lane & 7) ^ srow) * 8;
  const int frow = lane & 15;
  const int rcol = (((ks << 2) + (lane >> 4)) ^ (frow & 7)) * 8;

  f32x4 acc[4][4];
#pragma unroll
  for (int i = 0; i < 4; ++i)
#pragma unroll
    for (int j = 0; j < 4; ++j)
#pragma unroll
      for (int r = 0; r < 4; ++r) acc[i][j][r] = 0.f;

  auto stage = [&](int buf, int t) {
    const int k0 = t * 64;
#pragma unroll
    for (int h = 0; h < 2; ++h) {
      const int c = wave + h * 8;
      gload16(p.A + (size_t)(m0 + c * 8 + srow) * p.lda + k0 + scol,
              &sm[buf][0][0][0] + c * 512);
      gload16(p.B + (size_t)(n0 + c * 8 + srow) * p.ldb + k0 + scol,
              &sm[buf][1][0][0] + c * 512);
    }
  };

  const int nt = p.K / 64;
  stage(0, 0);
  int cur = 0;
  for (int t = 0; t < nt; ++t) {
    if (t + 1 < nt) {
      stage(cur ^ 1, t + 1);
      asm volatile("s_waitcnt vmcnt(4)" ::: "memory");
    } else {
      asm volatile("s_waitcnt vmcnt(0)" ::: "memory");
    }
    __builtin_amdgcn_s_barrier();

    bf16x8 af[4], bf_[4];
#pragma unroll
    for (int i = 0; i < 4; ++i)
      af[i] = *reinterpret_cast<const bf16x8*>(&sm[cur][0][wm0 + i * 16 + frow][rcol]);
#pragma unroll
    for (int j = 0; j < 4; ++j)
      bf_[j] = *reinterpret_cast<const bf16x8*>(&sm[cur][1][wn0 + j * 16 + frow][rcol]);
    __builtin_amdgcn_s_setprio(1);
#pragma unroll
    for (int i = 0; i < 4; ++i)
#pragma unroll
      for (int j = 0; j < 4; ++j)
        acc[i][j] = __builtin_amdgcn_mfma_f32_16x16x32_bf16(af[i], bf_[j], acc[i][j], 0, 0, 0);
    __builtin_amdgcn_s_setprio(0);

    if (t + 1 < nt) {
      asm volatile("s_waitcnt lgkmcnt(0)" ::: "memory");
      __builtin_amdgcn_s_barrier();
    }
    cur ^= 1;
  }

  // cross-K-slice reduce via LDS
  asm volatile("s_waitcnt lgkmcnt(0)" ::: "memory");
  __builtin_amdgcn_s_barrier();
  float* red = (float*)&sm[0][0][0][0];
  if (ks == 1) {
#pragma unroll
    for (int i = 0; i < 4; ++i)
#pragma unroll
      for (int j = 0; j < 4; ++j)
        *reinterpret_cast<f32x4*>(&red[sp * 4096 + (i * 4 + j) * 256 + lane * 4]) = acc[i][j];
    asm volatile("s_waitcnt lgkmcnt(0)" ::: "memory");
  }
  __builtin_amdgcn_s_barrier();
  if (ks == 0) {
#pragma unroll
    for (int i = 0; i < 4; ++i)
#pragma unroll
      for (int j = 0; j < 4; ++j) {
        f32x4 o = *reinterpret_cast<const f32x4*>(&red[sp * 4096 + (i * 4 + j) * 256 + lane * 4]);
#pragma unroll
        for (int r = 0; r < 4; ++r) acc[i][j][r] += o[r];
#pragma unroll
        for (int r = 0; r < 4; ++r)
          epilogue_store(p, m0 + wm0 + i * 16 + (lane >> 4) * 4 + r,
                         n0 + wn0 + j * 16 + (lane & 15), acc[i][j][r]);
      }
  }
}

// small output GEMM — R9 body (k-slot swizzled, conflict-free) + setprio
template<int BM, int BN>
__device__ __forceinline__ void gemm_body8(const GP p) {
  constexpr int BK = 32;
  constexpr int WM = BM / 2, WN = BN / 4;
  constexpr int FM = WM / 16, FN = WN / 16;
  __shared__ bf16 As[2][BM][BK];
  __shared__ bf16 Bs[2][BN][BK];
  const int lane = threadIdx.x & 63;
  const int wave = threadIdx.x >> 6;
  const int m0 = blockIdx.y * BM, n0 = blockIdx.x * BN;
  const int wm0 = (wave >> 2) * WM, wn0 = (wave & 3) * WN;
  const int srow = lane >> 2;
  const int scolE = (((lane & 3) ^ ((lane >> 3) & 3)) * 8);
  const int frow = lane & 15;
  const int rcolE = (((lane >> 4) ^ ((frow >> 1) & 3)) * 8);

  f32x4 acc[FM][FN];
#pragma unroll
  for (int i = 0; i < FM; ++i)
#pragma unroll
    for (int j = 0; j < FN; ++j)
#pragma unroll
      for (int r = 0; r < 4; ++r) acc[i][j][r] = 0.f;

  auto stage = [&](int buf, int t) {
    const int k0 = t * BK;
#pragma unroll
    for (int c = wave; c < BM / 16; c += 8) {
      const bf16* g = p.A + (size_t)(m0 + c * 16 + srow) * p.lda + k0 + scolE;
      gload16(g, &As[buf][0][0] + c * 512);
    }
#pragma unroll
    for (int c = wave; c < BN / 16; c += 8) {
      const bf16* g = p.B + (size_t)(n0 + c * 16 + srow) * p.ldb + k0 + scolE;
      gload16(g, &Bs[buf][0][0] + c * 512);
    }
  };

  const int nt = p.K / BK;
  stage(0, 0);
  __syncthreads();
  int cur = 0;
  for (int t = 0; t < nt; ++t) {
    if (t + 1 < nt) stage(cur ^ 1, t + 1);
    bf16x8 af[FM], bfrag[FN];
#pragma unroll
    for (int i = 0; i < FM; ++i)
      af[i] = *reinterpret_cast<const bf16x8*>(&As[cur][wm0 + i * 16 + frow][rcolE]);
#pragma unroll
    for (int j = 0; j < FN; ++j)
      bfrag[j] = *reinterpret_cast<const bf16x8*>(&Bs[cur][wn0 + j * 16 + frow][rcolE]);
    __builtin_amdgcn_s_setprio(1);
#pragma unroll
    for (int i = 0; i < FM; ++i)
#pragma unroll
      for (int j = 0; j < FN; ++j)
        acc[i][j] = __builtin_amdgcn_mfma_f32_16x16x32_bf16(af[i], bfrag[j], acc[i][j], 0, 0, 0);
    __builtin_amdgcn_s_setprio(0);
    __syncthreads();
    cur ^= 1;
  }

#pragma unroll
  for (int i = 0; i < FM; ++i)
#pragma unroll
    for (int j = 0; j < FN; ++j)
#pragma unroll
      for (int r = 0; r < 4; ++r)
        epilogue_store(p, m0 + wm0 + i * 16 + (lane >> 4) * 4 + r,
                       n0 + wn0 + j * 16 + (lane & 15), acc[i][j][r]);
}

__global__ __launch_bounds__(512) void k_tri(GP p0, GP p1, GP p2) {
  GP p;
  if (blockIdx.z == 0) p = p0;
  else if (blockIdx.z == 1) p = p1;
  else p = p2;
  gemm_ks(p);
}

__global__ __launch_bounds__(512) void k_split(GP p0, GP p1) {
  gemm_ks(blockIdx.z == 0 ? p0 : p1);
}

__global__ __launch_bounds__(512) void k_out(GP p) { gemm_body8<32, 64>(p); }

// elementwise: h = hb*0.9 + relu(P0+P1+radd+bias)*0.1 -> fp32 out; hb <- bf16 h
// P0/P1 are bf16 partials; hb is the bf16 h_in buffer, overwritten in place
// (each element read+written by exactly one thread).
__global__ __launch_bounds__(256) void k_epi(const bf16* __restrict__ P0,
                                             const bf16* __restrict__ P1,
                                             const float* __restrict__ radd,
                                             const float* __restrict__ bias,
                                             float* __restrict__ outf,
                                             bf16* __restrict__ hb) {
  int e = (blockIdx.x * 256 + threadIdx.x) * 8;
  int colb = e & (NN - 1);
  const bf16x8 a = *reinterpret_cast<const bf16x8*>(P0 + e);
  const bf16x8 b = *reinterpret_cast<const bf16x8*>(P1 + e);
  const bf16x8 hv = *reinterpret_cast<const bf16x8*>(hb + e);
  const float4 r0 = *reinterpret_cast<const float4*>(radd + e);
  const float4 r1 = *reinterpret_cast<const float4*>(radd + e + 4);
  const float4 c0 = *reinterpret_cast<const float4*>(bias + colb);
  const float4 c1 = *reinterpret_cast<const float4*>(bias + colb + 4);
  float pr[8] = {r0.x, r0.y, r0.z, r0.w, r1.x, r1.y, r1.z, r1.w};
  float pc[8] = {c0.x, c0.y, c0.z, c0.w, c1.x, c1.y, c1.z, c1.w};
  float4 o0, o1;
  bf16x8 nb;
#pragma unroll
  for (int j = 0; j < 8; ++j) {
    float pre = (float)a[j] + (float)b[j] + pr[j] + pc[j];
    float h = (float)hv[j] * 0.9f + fmaxf(pre, 0.f) * 0.1f;
    (j < 4 ? (&o0.x)[j] : (&o1.x)[j - 4]) = h;
    nb[j] = (bf16)h;
  }
  *reinterpret_cast<float4*>(outf + e) = o0;
  *reinterpret_cast<float4*>(outf + e + 4) = o1;
  *reinterpret_cast<bf16x8*>(hb + e) = nb;
}

// ---------------------------------------------------------------------------
extern "C" void kernel_launch(void* const* d_in, const int* in_sizes, int n_in,
                              void* d_out, int out_size, void* d_ws, size_t ws_size,
                              hipStream_t stream) {
  const float* x        = (const float*)d_in[0];
  const float* h0_in    = (const float*)d_in[1];
  const float* h1_in    = (const float*)d_in[2];
  const float* h2_in    = (const float*)d_in[3];
  const float* i_to_h0  = (const float*)d_in[4];
  const float* h0_w     = (const float*)d_in[5];
  const float* h0_b     = (const float*)d_in[6];
  const float* h0_to_h1 = (const float*)d_in[7];
  const float* h1_w     = (const float*)d_in[8];
  const float* h1_b     = (const float*)d_in[9];
  const float* h1_to_h2 = (const float*)d_in[10];
  const float* h2_w     = (const float*)d_in[11];
  const float* h2_b     = (const float*)d_in[12];
  const float* w_out    = (const float*)d_in[13];
  const float* m01      = (const float*)d_in[14];
  const float* m12      = (const float*)d_in[15];
  float* out = (float*)d_out;

  uint8_t* ws = (uint8_t*)d_ws;
  constexpr size_t OFF_A0  = 0;                    // [2048][2560] A of S0
  constexpr size_t OFF_W0  = OFF_A0 + 10485760;    // [2048][2560] B^T of S0
  constexpr size_t OFF_W1R = OFF_W0 + 10485760;    // [2048][2048] h1_w'^T
  constexpr size_t OFF_W2R = OFF_W1R + 8388608;    // [2048][2048] h2_w'^T
  constexpr size_t OFF_W01 = OFF_W2R + 8388608;    // [2048][2048] h01m^T
  constexpr size_t OFF_W12 = OFF_W01 + 8388608;    // [2048][2048] h12m^T
  constexpr size_t OFF_WO  = OFF_W12 + 8388608;    // [128][2048]  w_out^T
  constexpr size_t OFF_AR1 = OFF_WO + 524288;      // h1_in bf16 -> later h1 bf16
  constexpr size_t OFF_AR2 = OFF_AR1 + 8388608;    // h2_in bf16 -> later h2 bf16
  constexpr size_t OFF_AH0 = OFF_AR2 + 8388608;    // h0 bf16
  constexpr size_t WS_NEED = OFF_AH0 + 8388608;    // ~80.2 MB
  if (ws_size < WS_NEED) return;

  bf16* A0  = (bf16*)(ws + OFF_A0);
  bf16* Wt0 = (bf16*)(ws + OFF_W0);
  bf16* W1r = (bf16*)(ws + OFF_W1R);
  bf16* W2r = (bf16*)(ws + OFF_W2R);
  bf16* W01 = (bf16*)(ws + OFF_W01);
  bf16* W12 = (bf16*)(ws + OFF_W12);
  bf16* WtO = (bf16*)(ws + OFF_WO);
  bf16* Ar1 = (bf16*)(ws + OFF_AR1);
  bf16* Ar2 = (bf16*)(ws + OFF_AR2);
  bf16* Ah0 = (bf16*)(ws + OFF_AH0);
  bf16* Ah1 = Ar1;   // h1_in bf16 dead after D1 (k_epi converts in place)
  bf16* Ah2 = Ar2;
  // bf16 split-K partials in the A0/Wt0 region (dead after D1): 16 MB used.
  bf16* P0b = (bf16*)(ws + 0);
  bf16* P1b = (bf16*)(ws + 8388608);

  float* o_h0  = out;
  float* o_h1  = out + (size_t)BB * NN;
  float* o_h2  = out + (size_t)2 * BB * NN;
  float* o_out = out + (size_t)3 * BB * NN;

  // --- fused prep (1 dispatch) ---
  PAll pa;
  int n8a = BB * ISZ / 8;
  int n8b = n8a + BB * NN / 8;
  int n8c = n8b + BB * NN / 8;
  int n8d = n8c + BB * NN / 8;
  pa.p[0] = {x,     A0,  ISZ, ISZ + NN, 0,   n8a};
  pa.p[1] = {h0_in, A0,  NN,  ISZ + NN, ISZ, n8b};
  pa.p[2] = {h1_in, Ar1, NN,  NN,       0,   n8c};
  pa.p[3] = {h2_in, Ar2, NN,  NN,       0,   n8d};
  pa.packBlocks = (n8d + 255) / 256;
  int s0 = 0;
  pa.d[0] = {i_to_h0,  nullptr, Wt0, NN,  ISZ + NN, 0,   0, ISZ / 128, s0}; s0 += (ISZ / 128) * (NN / 32);
  pa.d[1] = {h0_w,     nullptr, Wt0, NN,  ISZ + NN, ISZ, 1, NN / 128,  s0}; s0 += (NN / 128) * (NN / 32);
  pa.d[2] = {h1_w,     nullptr, W1r, NN,  NN,       0,   1, NN / 128,  s0}; s0 += (NN / 128) * (NN / 32);
  pa.d[3] = {h2_w,     nullptr, W2r, NN,  NN,       0,   1, NN / 128,  s0}; s0 += (NN / 128) * (NN / 32);
  pa.d[4] = {h0_to_h1, m01,     W01, NN,  NN,       0,   2, NN / 128,  s0}; s0 += (NN / 128) * (NN / 32);
  pa.d[5] = {h1_to_h2, m12,     W12, NN,  NN,       0,   2, NN / 128,  s0}; s0 += (NN / 128) * (NN / 32);
  pa.d[6] = {w_out,    nullptr, WtO, OSZ, NN,       0,   0, NN / 128,  s0}; s0 += (NN / 128) * (OSZ / 32);
  prep_all_k<<<pa.packBlocks + s0, 256, 0, stream>>>(pa);

  // --- D1: S0 (h0) + R1 + R2, 768 blocks of 8 waves, 128x128 K-split body ---
  GP pS0{A0,  Wt0, ISZ + NN, ISZ + NN, ISZ + NN, h0_in, h0_b, nullptr,
         o_h0, NN, Ah0, NN, 0};
  GP pR1{Ar1, W1r, NN, NN, NN, nullptr, nullptr, nullptr, o_h1, NN, nullptr, 0, 1};
  GP pR2{Ar2, W2r, NN, NN, NN, nullptr, nullptr, nullptr, o_h2, NN, nullptr, 0, 1};
  k_tri<<<dim3(NN / 128, BB / 128, 3), 512, 0, stream>>>(pS0, pR1, pR2);

  // --- D2: F1 = h0@W01 split-K=2 (512 blocks, bf16 partials); combine -> h1 ---
  GP pG1a{Ah0,          W01,          NN / 2, NN, NN, nullptr, nullptr, nullptr, (float*)P0b, NN, nullptr, 0, 2};
  GP pG1b{Ah0 + NN / 2, W01 + NN / 2, NN / 2, NN, NN, nullptr, nullptr, nullptr, (float*)P1b, NN, nullptr, 0, 2};
  k_split<<<dim3(NN / 128, BB / 128, 2), 512, 0, stream>>>(pG1a, pG1b);
  k_epi<<<BB * NN / 2048, 256, 0, stream>>>(P0b, P1b, o_h1, h1_b, o_h1, Ah1);

  // --- D3: F2 = h1@W12 split-K=2; combine -> h2 ---
  GP pG2a{Ah1,          W12,          NN / 2, NN, NN, nullptr, nullptr, nullptr, (float*)P0b, NN, nullptr, 0, 2};
  GP pG2b{Ah1 + NN / 2, W12 + NN / 2, NN / 2, NN, NN, nullptr, nullptr, nullptr, (float*)P1b, NN, nullptr, 0, 2};
  k_split<<<dim3(NN / 128, BB / 128, 2), 512, 0, stream>>>(pG2a, pG2b);
  k_epi<<<BB * NN / 2048, 256, 0, stream>>>(P0b, P1b, o_h2, h2_b, o_h2, Ah2);

  // --- D4: out = h2 @ w_out ---
  GP pO{Ah2, WtO, NN, NN, NN, nullptr, nullptr, nullptr, o_out, OSZ, nullptr, 0, 1};
  k_out<<<dim3(OSZ / 64, BB / 32), 512, 0, stream>>>(pO);
}

// Round 13
// 214.181 us; speedup vs baseline: 1.0075x; 1.0075x over previous
//
#include <hip/hip_runtime.h>
#include <hip/hip_bf16.h>
#include <stdint.h>

typedef __bf16 bf16;
typedef __bf16 bf16x8 __attribute__((ext_vector_type(8)));
typedef float f32x4 __attribute__((ext_vector_type(4)));

#define BB   2048
#define ISZ  512
#define NN   2048
#define OSZ  128

// ---------------------------------------------------------------------------
// Prep: 4 pack regions (fp32 -> bf16, 8 elems/thread) + 4 early transposes
// (tile 128k x 32n, wide I/O).  W01/W12/WtO transposes are DEFERRED into the
// D1 dispatch's z=3 slice (they're only needed by D2/D3/D4 and D1 leaves
// BW/CU headroom).
// ---------------------------------------------------------------------------
struct PackD { const float* src; bf16* dst; int W, ld, off, n8; };
struct TD    { const float* src; const float* msk; bf16* dst;
               int Ncols, ld_dst, k_off, mode, ntk, start; };
struct PAll  { PackD p[4]; TD d[7]; int packBlocks; };
struct TDef  { TD d[3]; int total; };

__global__ __launch_bounds__(256) void prep_all_k(PAll a) {
  if ((int)blockIdx.x < a.packBlocks) {
    int idx = blockIdx.x * 256 + threadIdx.x;
    PackD d = a.p[0]; int base = 0;
#pragma unroll
    for (int i = 1; i < 4; ++i) if (idx >= a.p[i - 1].n8) { d = a.p[i]; base = a.p[i - 1].n8; }
    if (idx >= d.n8) return;
    int e = (idx - base) * 8;
    int m = e / d.W;
    int c = e - m * d.W;
    const float4 v0 = *reinterpret_cast<const float4*>(d.src + e);
    const float4 v1 = *reinterpret_cast<const float4*>(d.src + e + 4);
    bf16x8 o;
    o[0] = (bf16)v0.x; o[1] = (bf16)v0.y; o[2] = (bf16)v0.z; o[3] = (bf16)v0.w;
    o[4] = (bf16)v1.x; o[5] = (bf16)v1.y; o[6] = (bf16)v1.z; o[7] = (bf16)v1.w;
    *reinterpret_cast<bf16x8*>(d.dst + (size_t)m * d.ld + d.off + c) = o;
    return;
  }
  int bid = blockIdx.x - a.packBlocks;
  TD d = a.d[0];
#pragma unroll
  for (int i = 1; i < 7; ++i) if (bid >= a.d[i].start) d = a.d[i];
  int local = bid - d.start;
  int k0 = (local % d.ntk) * 128;
  int n0 = (local / d.ntk) * 32;
  __shared__ float t[128][33];
  const int tx8 = threadIdx.x & 7;
  const int kr  = threadIdx.x >> 3;
  const int nc  = n0 + tx8 * 4;
#pragma unroll
  for (int i = 0; i < 4; ++i) {
    int k = k0 + kr + 32 * i;
    float4 v = *reinterpret_cast<const float4*>(d.src + (size_t)k * d.Ncols + nc);
    if (d.mode == 2) {
      float4 m = *reinterpret_cast<const float4*>(d.msk + (size_t)k * d.Ncols + nc);
      v.x *= m.x; v.y *= m.y; v.z *= m.z; v.w *= m.w;
    } else if (d.mode == 1) {
      if (k == nc)     v.x = 0.f;
      if (k == nc + 1) v.y = 0.f;
      if (k == nc + 2) v.z = 0.f;
      if (k == nc + 3) v.w = 0.f;
    }
    float* r = &t[kr + 32 * i][tx8 * 4];
    r[0] = v.x; r[1] = v.y; r[2] = v.z; r[3] = v.w;
  }
  __syncthreads();
  const int n  = threadIdx.x >> 3;
  const int kc = (threadIdx.x & 7) * 16;
  bf16x8 o0, o1;
#pragma unroll
  for (int j = 0; j < 8; ++j) {
    o0[j] = (bf16)t[kc + j][n];
    o1[j] = (bf16)t[kc + 8 + j][n];
  }
  bf16* dp = d.dst + (size_t)(n0 + n) * d.ld_dst + d.k_off + k0 + kc;
  *reinterpret_cast<bf16x8*>(dp) = o0;
  *reinterpret_cast<bf16x8*>(dp + 8) = o1;
}

// ---------------------------------------------------------------------------
// GEMM descriptor; epi 0: pre = acc + bias[col] (+ radd);
// h = hin*0.9 + relu(pre)*0.1 -> fp32 outf + bf16 nxt.   epi 1: fp32 acc.
// ---------------------------------------------------------------------------
struct GP {
  const bf16* A; const bf16* B;
  int K, lda, ldb;
  const float* hin; const float* bias; const float* radd;
  float* outf; int ld_out;
  bf16* nxt; int ld_nxt;
  int epi;
};

__device__ __forceinline__ void gload16(const bf16* g, bf16* l) {
  __builtin_amdgcn_global_load_lds(
      (const __attribute__((address_space(1))) void*)g,
      (__attribute__((address_space(3))) void*)l, 16, 0, 0);
}

__device__ __forceinline__ void epilogue_store(const GP& p, int row, int col, float v) {
  size_t oidx = (size_t)row * p.ld_out + col;
  if (p.epi == 0) {
    float pre = v + p.bias[col];
    if (p.radd) pre += p.radd[oidx];
    float h = p.hin[oidx] * 0.9f + fmaxf(pre, 0.f) * 0.1f;
    p.outf[oidx] = h;
    p.nxt[(size_t)row * p.ld_nxt + col] = (bf16)h;
  } else {
    p.outf[oidx] = v;
  }
}

// ---------------------------------------------------------------------------
// R10/R11 winner body: 128x128 tile, 8 waves = 2x2 spatial (64x64 wave-tile)
// x 2 K-slices, BK=64, dbuf 64 KB LDS (passed in), counted vmcnt, cross-
// slice LDS reduce, conflict-free swizzle.  Measured: D1 89-94 us, 0 bank
// conflicts.
// ---------------------------------------------------------------------------
__device__ __forceinline__ void gemm_ks(const GP p, uint8_t* smraw) {
  typedef bf16 smT[2][128][64];
  smT* sm = (smT*)smraw;                              // sm[buf][A/B][row][col]
  const int lane = threadIdx.x & 63;
  const int wave = threadIdx.x >> 6;
  const int ks = wave >> 2;
  const int sp = wave & 3;
  const int gx = gridDim.x, nwg = gx * gridDim.y;
  const int lid = blockIdx.x + gx * blockIdx.y;
  const int q = nwg >> 3;
  const int swz = (lid & 7) * q + (lid >> 3);
  const int m0 = (swz / gx) * 128, n0 = (swz % gx) * 128;
  const int wm0 = (sp >> 1) * 64, wn0 = (sp & 1) * 64;
  const int srow = lane >> 3;
  const int scol = ((lane & 7) ^ srow) * 8;
  const int frow = lane & 15;
  const int rcol = (((ks << 2) + (lane >> 4)) ^ (frow & 7)) * 8;

  f32x4 acc[4][4];
#pragma unroll
  for (int i = 0; i < 4; ++i)
#pragma unroll
    for (int j = 0; j < 4; ++j)
#pragma unroll
      for (int r = 0; r < 4; ++r) acc[i][j][r] = 0.f;

  auto stage = [&](int buf, int t) {
    const int k0 = t * 64;
#pragma unroll
    for (int h = 0; h < 2; ++h) {
      const int c = wave + h * 8;
      gload16(p.A + (size_t)(m0 + c * 8 + srow) * p.lda + k0 + scol,
              &sm[buf][0][0][0] + c * 512);
      gload16(p.B + (size_t)(n0 + c * 8 + srow) * p.ldb + k0 + scol,
              &sm[buf][1][0][0] + c * 512);
    }
  };

  const int nt = p.K / 64;
  stage(0, 0);
  int cur = 0;
  for (int t = 0; t < nt; ++t) {
    if (t + 1 < nt) {
      stage(cur ^ 1, t + 1);
      asm volatile("s_waitcnt vmcnt(4)" ::: "memory");
    } else {
      asm volatile("s_waitcnt vmcnt(0)" ::: "memory");
    }
    __builtin_amdgcn_s_barrier();

    bf16x8 af[4], bf_[4];
#pragma unroll
    for (int i = 0; i < 4; ++i)
      af[i] = *reinterpret_cast<const bf16x8*>(&sm[cur][0][wm0 + i * 16 + frow][rcol]);
#pragma unroll
    for (int j = 0; j < 4; ++j)
      bf_[j] = *reinterpret_cast<const bf16x8*>(&sm[cur][1][wn0 + j * 16 + frow][rcol]);
#pragma unroll
    for (int i = 0; i < 4; ++i)
#pragma unroll
      for (int j = 0; j < 4; ++j)
        acc[i][j] = __builtin_amdgcn_mfma_f32_16x16x32_bf16(af[i], bf_[j], acc[i][j], 0, 0, 0);

    if (t + 1 < nt) {
      asm volatile("s_waitcnt lgkmcnt(0)" ::: "memory");
      __builtin_amdgcn_s_barrier();
    }
    cur ^= 1;
  }

  asm volatile("s_waitcnt lgkmcnt(0)" ::: "memory");
  __builtin_amdgcn_s_barrier();
  float* red = (float*)smraw;
  if (ks == 1) {
#pragma unroll
    for (int i = 0; i < 4; ++i)
#pragma unroll
      for (int j = 0; j < 4; ++j)
        *reinterpret_cast<f32x4*>(&red[sp * 4096 + (i * 4 + j) * 256 + lane * 4]) = acc[i][j];
    asm volatile("s_waitcnt lgkmcnt(0)" ::: "memory");
  }
  __builtin_amdgcn_s_barrier();
  if (ks == 0) {
#pragma unroll
    for (int i = 0; i < 4; ++i)
#pragma unroll
      for (int j = 0; j < 4; ++j) {
        f32x4 o = *reinterpret_cast<const f32x4*>(&red[sp * 4096 + (i * 4 + j) * 256 + lane * 4]);
#pragma unroll
        for (int r = 0; r < 4; ++r) acc[i][j][r] += o[r];
#pragma unroll
        for (int r = 0; r < 4; ++r)
          epilogue_store(p, m0 + wm0 + i * 16 + (lane >> 4) * 4 + r,
                         n0 + wn0 + j * 16 + (lane & 15), acc[i][j][r]);
      }
  }
}

// 512-thread deferred transpose: tile 128(k) x 64(n), fp32 -> bf16^T.
// active-predicated body with unconditional barriers (uniform loop count).
__device__ __forceinline__ void transpose512(const TD& d, int tile, bool active,
                                             uint8_t* smraw) {
  float (*t)[65] = (float (*)[65])smraw;   // [128][65] floats = 33.3 KB
  int k0 = 0, n0 = 0;
  if (active) { k0 = (tile % d.ntk) * 128; n0 = (tile / d.ntk) * 64; }
  const int tx = threadIdx.x & 15;
  const int kr = threadIdx.x >> 4;         // 0..31
  const int nc = n0 + tx * 4;
  if (active) {
#pragma unroll
    for (int i = 0; i < 4; ++i) {
      int k = k0 + kr + 32 * i;
      float4 v = *reinterpret_cast<const float4*>(d.src + (size_t)k * d.Ncols + nc);
      if (d.mode == 2) {
        float4 m = *reinterpret_cast<const float4*>(d.msk + (size_t)k * d.Ncols + nc);
        v.x *= m.x; v.y *= m.y; v.z *= m.z; v.w *= m.w;
      }
      float* r = &t[kr + 32 * i][tx * 4];
      r[0] = v.x; r[1] = v.y; r[2] = v.z; r[3] = v.w;
    }
  }
  __syncthreads();
  if (active) {
    const int n  = threadIdx.x >> 3;       // 0..63
    const int kc = (threadIdx.x & 7) * 16;
    bf16x8 o0, o1;
#pragma unroll
    for (int j = 0; j < 8; ++j) {
      o0[j] = (bf16)t[kc + j][n0 + n - n0 + n * 0 + n]; // t[kc+j][n]
      o1[j] = (bf16)t[kc + 8 + j][n];
    }
    // (o0 index simplification)
#pragma unroll
    for (int j = 0; j < 8; ++j) o0[j] = (bf16)t[kc + j][n];
    bf16* dp = d.dst + (size_t)(n0 + n) * d.ld_dst + d.k_off + k0 + kc;
    *reinterpret_cast<bf16x8*>(dp) = o0;
    *reinterpret_cast<bf16x8*>(dp + 8) = o1;
  }
  __syncthreads();
}

__global__ __launch_bounds__(512) void k_tri(GP p0, GP p1, GP p2, TDef td) {
  __shared__ __align__(16) uint8_t smraw[65536];
  if (blockIdx.z < 3) {
    GP p;
    if (blockIdx.z == 0) p = p0;
    else if (blockIdx.z == 1) p = p1;
    else p = p2;
    gemm_ks(p, smraw);
    return;
  }
  // z == 3: deferred transposes (grid-stride over tiles)
  const int bid = blockIdx.x + gridDim.x * blockIdx.y;   // 0..255
  const int nb = gridDim.x * gridDim.y;
  const int iters = (td.total + nb - 1) / nb;
  for (int it = 0; it < iters; ++it) {
    int tile = it * nb + bid;
    TD d = td.d[0];
    if (tile >= td.d[1].start) d = td.d[1];
    if (tile >= td.d[2].start) d = td.d[2];
    int local = tile - d.start;
    transpose512(d, local, tile < td.total, smraw);
  }
}

__global__ __launch_bounds__(512) void k_split(GP p0, GP p1) {
  __shared__ __align__(16) uint8_t smraw[65536];
  gemm_ks(blockIdx.z == 0 ? p0 : p1, smraw);
}

// small output GEMM — R9 body (k-slot swizzled, conflict-free)
template<int BM, int BN>
__device__ __forceinline__ void gemm_body8(const GP p) {
  constexpr int BK = 32;
  constexpr int WM = BM / 2, WN = BN / 4;
  constexpr int FM = WM / 16, FN = WN / 16;
  __shared__ bf16 As[2][BM][BK];
  __shared__ bf16 Bs[2][BN][BK];
  const int lane = threadIdx.x & 63;
  const int wave = threadIdx.x >> 6;
  const int m0 = blockIdx.y * BM, n0 = blockIdx.x * BN;
  const int wm0 = (wave >> 2) * WM, wn0 = (wave & 3) * WN;
  const int srow = lane >> 2;
  const int scolE = (((lane & 3) ^ ((lane >> 3) & 3)) * 8);
  const int frow = lane & 15;
  const int rcolE = (((lane >> 4) ^ ((frow >> 1) & 3)) * 8);

  f32x4 acc[FM][FN];
#pragma unroll
  for (int i = 0; i < FM; ++i)
#pragma unroll
    for (int j = 0; j < FN; ++j)
#pragma unroll
      for (int r = 0; r < 4; ++r) acc[i][j][r] = 0.f;

  auto stage = [&](int buf, int t) {
    const int k0 = t * BK;
#pragma unroll
    for (int c = wave; c < BM / 16; c += 8) {
      const bf16* g = p.A + (size_t)(m0 + c * 16 + srow) * p.lda + k0 + scolE;
      gload16(g, &As[buf][0][0] + c * 512);
    }
#pragma unroll
    for (int c = wave; c < BN / 16; c += 8) {
      const bf16* g = p.B + (size_t)(n0 + c * 16 + srow) * p.ldb + k0 + scolE;
      gload16(g, &Bs[buf][0][0] + c * 512);
    }
  };

  const int nt = p.K / BK;
  stage(0, 0);
  __syncthreads();
  int cur = 0;
  for (int t = 0; t < nt; ++t) {
    if (t + 1 < nt) stage(cur ^ 1, t + 1);
    bf16x8 af[FM], bfrag[FN];
#pragma unroll
    for (int i = 0; i < FM; ++i)
      af[i] = *reinterpret_cast<const bf16x8*>(&As[cur][wm0 + i * 16 + frow][rcolE]);
#pragma unroll
    for (int j = 0; j < FN; ++j)
      bfrag[j] = *reinterpret_cast<const bf16x8*>(&Bs[cur][wn0 + j * 16 + frow][rcolE]);
#pragma unroll
    for (int i = 0; i < FM; ++i)
#pragma unroll
      for (int j = 0; j < FN; ++j)
        acc[i][j] = __builtin_amdgcn_mfma_f32_16x16x32_bf16(af[i], bfrag[j], acc[i][j], 0, 0, 0);
    __syncthreads();
    cur ^= 1;
  }

#pragma unroll
  for (int i = 0; i < FM; ++i)
#pragma unroll
    for (int j = 0; j < FN; ++j)
#pragma unroll
      for (int r = 0; r < 4; ++r)
        epilogue_store(p, m0 + wm0 + i * 16 + (lane >> 4) * 4 + r,
                       n0 + wn0 + j * 16 + (lane & 15), acc[i][j][r]);
}

__global__ __launch_bounds__(512) void k_out(GP p) { gemm_body8<32, 64>(p); }

// elementwise: h = hin*0.9 + relu(P0+P1+radd+bias)*0.1 -> fp32 out + bf16 nxt
__global__ __launch_bounds__(256) void k_epi(const float* __restrict__ P0,
                                             const float* __restrict__ P1,
                                             const float* __restrict__ radd,
                                             const float* __restrict__ hin,
                                             const float* __restrict__ bias,
                                             float* __restrict__ outf,
                                             bf16* __restrict__ nxt) {
  int e = (blockIdx.x * 256 + threadIdx.x) * 8;
  int colb = e & (NN - 1);
  const float4 a0 = *reinterpret_cast<const float4*>(P0 + e);
  const float4 a1 = *reinterpret_cast<const float4*>(P0 + e + 4);
  const float4 b0 = *reinterpret_cast<const float4*>(P1 + e);
  const float4 b1 = *reinterpret_cast<const float4*>(P1 + e + 4);
  const float4 r0 = *reinterpret_cast<const float4*>(radd + e);
  const float4 r1 = *reinterpret_cast<const float4*>(radd + e + 4);
  const float4 h0 = *reinterpret_cast<const float4*>(hin + e);
  const float4 h1 = *reinterpret_cast<const float4*>(hin + e + 4);
  const float4 c0 = *reinterpret_cast<const float4*>(bias + colb);
  const float4 c1 = *reinterpret_cast<const float4*>(bias + colb + 4);
  float pa[8] = {a0.x, a0.y, a0.z, a0.w, a1.x, a1.y, a1.z, a1.w};
  float pb[8] = {b0.x, b0.y, b0.z, b0.w, b1.x, b1.y, b1.z, b1.w};
  float pr[8] = {r0.x, r0.y, r0.z, r0.w, r1.x, r1.y, r1.z, r1.w};
  float ph[8] = {h0.x, h0.y, h0.z, h0.w, h1.x, h1.y, h1.z, h1.w};
  float pc[8] = {c0.x, c0.y, c0.z, c0.w, c1.x, c1.y, c1.z, c1.w};
  float4 o0, o1;
  bf16x8 nb;
#pragma unroll
  for (int j = 0; j < 8; ++j) {
    float pre = pa[j] + pb[j] + pr[j] + pc[j];
    float h = ph[j] * 0.9f + fmaxf(pre, 0.f) * 0.1f;
    (j < 4 ? (&o0.x)[j] : (&o1.x)[j - 4]) = h;
    nb[j] = (bf16)h;
  }
  *reinterpret_cast<float4*>(outf + e) = o0;
  *reinterpret_cast<float4*>(outf + e + 4) = o1;
  *reinterpret_cast<bf16x8*>(nxt + e) = nb;
}

// ---------------------------------------------------------------------------
extern "C" void kernel_launch(void* const* d_in, const int* in_sizes, int n_in,
                              void* d_out, int out_size, void* d_ws, size_t ws_size,
                              hipStream_t stream) {
  const float* x        = (const float*)d_in[0];
  const float* h0_in    = (const float*)d_in[1];
  const float* h1_in    = (const float*)d_in[2];
  const float* h2_in    = (const float*)d_in[3];
  const float* i_to_h0  = (const float*)d_in[4];
  const float* h0_w     = (const float*)d_in[5];
  const float* h0_b     = (const float*)d_in[6];
  const float* h0_to_h1 = (const float*)d_in[7];
  const float* h1_w     = (const float*)d_in[8];
  const float* h1_b     = (const float*)d_in[9];
  const float* h1_to_h2 = (const float*)d_in[10];
  const float* h2_w     = (const float*)d_in[11];
  const float* h2_b     = (const float*)d_in[12];
  const float* w_out    = (const float*)d_in[13];
  const float* m01      = (const float*)d_in[14];
  const float* m12      = (const float*)d_in[15];
  float* out = (float*)d_out;

  uint8_t* ws = (uint8_t*)d_ws;
  constexpr size_t OFF_A0  = 0;                    // [2048][2560] A of S0
  constexpr size_t OFF_W0  = OFF_A0 + 10485760;    // [2048][2560] B^T of S0
  constexpr size_t OFF_W1R = OFF_W0 + 10485760;    // [2048][2048] h1_w'^T
  constexpr size_t OFF_W2R = OFF_W1R + 8388608;    // [2048][2048] h2_w'^T
  constexpr size_t OFF_W01 = OFF_W2R + 8388608;    // [2048][2048] h01m^T
  constexpr size_t OFF_W12 = OFF_W01 + 8388608;    // [2048][2048] h12m^T
  constexpr size_t OFF_WO  = OFF_W12 + 8388608;    // [128][2048]  w_out^T
  constexpr size_t OFF_AR1 = OFF_WO + 524288;      // h1_in bf16 -> later h1 bf16
  constexpr size_t OFF_AR2 = OFF_AR1 + 8388608;    // h2_in bf16 -> later h2 bf16
  constexpr size_t OFF_AH0 = OFF_AR2 + 8388608;    // h0 bf16
  constexpr size_t WS_NEED = OFF_AH0 + 8388608;    // ~80.2 MB
  if (ws_size < WS_NEED) return;

  bf16* A0  = (bf16*)(ws + OFF_A0);
  bf16* Wt0 = (bf16*)(ws + OFF_W0);
  bf16* W1r = (bf16*)(ws + OFF_W1R);
  bf16* W2r = (bf16*)(ws + OFF_W2R);
  bf16* W01 = (bf16*)(ws + OFF_W01);
  bf16* W12 = (bf16*)(ws + OFF_W12);
  bf16* WtO = (bf16*)(ws + OFF_WO);
  bf16* Ar1 = (bf16*)(ws + OFF_AR1);
  bf16* Ar2 = (bf16*)(ws + OFF_AR2);
  bf16* Ah0 = (bf16*)(ws + OFF_AH0);
  bf16* Ah1 = Ar1;   // h1_in bf16 dead after D1
  bf16* Ah2 = Ar2;
  // fp32 split-K partials in regions dead after D1 (A0..W2r, 33.6 < 37.7 MB)
  float* P0 = (float*)(ws + 0);
  float* P1 = (float*)(ws + 16777216);

  float* o_h0  = out;
  float* o_h1  = out + (size_t)BB * NN;
  float* o_h2  = out + (size_t)2 * BB * NN;
  float* o_out = out + (size_t)3 * BB * NN;

  // --- prep (packs + 4 early transposes) ---
  PAll pa;
  int n8a = BB * ISZ / 8;
  int n8b = n8a + BB * NN / 8;
  int n8c = n8b + BB * NN / 8;
  int n8d = n8c + BB * NN / 8;
  pa.p[0] = {x,     A0,  ISZ, ISZ + NN, 0,   n8a};
  pa.p[1] = {h0_in, A0,  NN,  ISZ + NN, ISZ, n8b};
  pa.p[2] = {h1_in, Ar1, NN,  NN,       0,   n8c};
  pa.p[3] = {h2_in, Ar2, NN,  NN,       0,   n8d};
  pa.packBlocks = (n8d + 255) / 256;
  int s0 = 0;
  pa.d[0] = {i_to_h0, nullptr, Wt0, NN, ISZ + NN, 0,   0, ISZ / 128, s0}; s0 += (ISZ / 128) * (NN / 32);
  pa.d[1] = {h0_w,    nullptr, Wt0, NN, ISZ + NN, ISZ, 1, NN / 128,  s0}; s0 += (NN / 128) * (NN / 32);
  pa.d[2] = {h1_w,    nullptr, W1r, NN, NN,       0,   1, NN / 128,  s0}; s0 += (NN / 128) * (NN / 32);
  pa.d[3] = {h2_w,    nullptr, W2r, NN, NN,       0,   1, NN / 128,  s0}; s0 += (NN / 128) * (NN / 32);
  pa.d[4] = pa.d[3]; pa.d[4].start = 0x7FFFFFFF;
  pa.d[5] = pa.d[4];
  pa.d[6] = pa.d[4];
  prep_all_k<<<pa.packBlocks + s0, 256, 0, stream>>>(pa);

  // --- deferred transposes (ride inside D1's dispatch, z=3) ---
  TDef td;
  int t0 = 0;
  td.d[0] = {h0_to_h1, m01, W01, NN,  NN, 0, 2, NN / 128, t0}; t0 += (NN / 128) * (NN / 64);
  td.d[1] = {h1_to_h2, m12, W12, NN,  NN, 0, 2, NN / 128, t0}; t0 += (NN / 128) * (NN / 64);
  td.d[2] = {w_out,  nullptr, WtO, OSZ, NN, 0, 0, NN / 128, t0}; t0 += (NN / 128) * (OSZ / 64);
  td.total = t0;   // 1056

  // --- D1: S0 (h0) + R1 + R2 (768 GEMM blocks) + z=3 transpose slice ---
  GP pS0{A0,  Wt0, ISZ + NN, ISZ + NN, ISZ + NN, h0_in, h0_b, nullptr,
         o_h0, NN, Ah0, NN, 0};
  GP pR1{Ar1, W1r, NN, NN, NN, nullptr, nullptr, nullptr, o_h1, NN, nullptr, 0, 1};
  GP pR2{Ar2, W2r, NN, NN, NN, nullptr, nullptr, nullptr, o_h2, NN, nullptr, 0, 1};
  k_tri<<<dim3(NN / 128, BB / 128, 4), 512, 0, stream>>>(pS0, pR1, pR2, td);

  // --- D2: F1 = h0@W01 split-K=2 (512 blocks); combine with R1 -> h1 ---
  GP pG1a{Ah0,          W01,          NN / 2, NN, NN, nullptr, nullptr, nullptr, P0, NN, nullptr, 0, 1};
  GP pG1b{Ah0 + NN / 2, W01 + NN / 2, NN / 2, NN, NN, nullptr, nullptr, nullptr, P1, NN, nullptr, 0, 1};
  k_split<<<dim3(NN / 128, BB / 128, 2), 512, 0, stream>>>(pG1a, pG1b);
  k_epi<<<BB * NN / 2048, 256, 0, stream>>>(P0, P1, o_h1, h1_in, h1_b, o_h1, Ah1);

  // --- D3: F2 = h1@W12 split-K=2; combine with R2 -> h2 ---
  GP pG2a{Ah1,          W12,          NN / 2, NN, NN, nullptr, nullptr, nullptr, P0, NN, nullptr, 0, 1};
  GP pG2b{Ah1 + NN / 2, W12 + NN / 2, NN / 2, NN, NN, nullptr, nullptr, nullptr, P1, NN, nullptr, 0, 1};
  k_split<<<dim3(NN / 128, BB / 128, 2), 512, 0, stream>>>(pG2a, pG2b);
  k_epi<<<BB * NN / 2048, 256, 0, stream>>>(P0, P1, o_h2, h2_in, h2_b, o_h2, Ah2);

  // --- D4: out = h2 @ w_out ---
  GP pO{Ah2, WtO, NN, NN, NN, nullptr, nullptr, nullptr, o_out, OSZ, nullptr, 0, 1};
  k_out<<<dim3(OSZ / 64, BB / 32), 512, 0, stream>>>(pO);
}